// Round 3
// baseline (3089.168 us; speedup 1.0000x reference)
//
#include <hip/hip_runtime.h>
#include <math.h>

// Problem constants
#define NSEQ 4
#define BATCH 256
#define T 64
#define FIN 32
#define S 512

// Decomposition: 64 batch-groups x 4 rows, 4 S-slices x 128 cols -> 256 WGs
#define RPG 4        // rows per group
#define SLICES 4     // WGs per group
#define SW 128       // slice width (s-columns per WG)
#define NT 256
#define NWG 256
#define NGRP 64

// Workspace layout (float element offsets). TBS = T*BATCH*S.
#define TBS 8388608ull
#define XW_OFF 0ull              // [T][B][S] x@Wx + bias, per-lane, per-WG-slice private
#define ST0_OFF TBS              // states ping  [T][B][S]
#define ST1_OFF (2ull * TBS)     // states pong  [T][B][S]
#define CTL_OFF (3ull * TBS)     // uints: [0]=gcnt [1]=gflg, [8+g*4]=cnt_g [8+g*4+1]=flg_g
// total ws: 3*TBS*4 + ~1.1 KB  (R1/R2 used +4 KB and passed -> fits)

#define FLAG_MAGIC 0x13572468u

// ---- coherent (cross-XCD) access: L1/L2-bypassing b128 loads ------------
// sc0 sc1 => device-coherent, served at the Infinity Cache. b128 + contiguous
// 32 B per lane = fully-packed EA sectors (R2's scalar 2KB-stride cloads were
// 8x over-fetch + 16x the request count -> the 1 GB FETCH_SIZE).
__device__ __forceinline__ void cload8(float4& a, float4& b, const float* p) {
  asm volatile(
      "global_load_dwordx4 %0, %2, off sc0 sc1\n\t"
      "global_load_dwordx4 %1, %2, off offset:16 sc0 sc1\n\t"
      "s_waitcnt vmcnt(0)"
      : "=&v"(a), "=&v"(b) : "v"(p) : "memory");
}
__device__ __forceinline__ void cload16(float4& a, float4& b, float4& c, float4& d,
                                        const float* p, const float* q) {
  asm volatile(
      "global_load_dwordx4 %0, %4, off sc0 sc1\n\t"
      "global_load_dwordx4 %1, %4, off offset:16 sc0 sc1\n\t"
      "global_load_dwordx4 %2, %5, off sc0 sc1\n\t"
      "global_load_dwordx4 %3, %5, off offset:16 sc0 sc1\n\t"
      "s_waitcnt vmcnt(0)"
      : "=&v"(a), "=&v"(b), "=&v"(c), "=&v"(d) : "v"(p), "v"(q) : "memory");
}
__device__ __forceinline__ void cstore1(float* p, float v) {
  asm volatile("global_store_dword %0, %1, off sc0 sc1" :: "v"(p), "v"(v) : "memory");
}

__device__ __forceinline__ void fma4(float4& acc, float s, const float4& v) {
  acc.x = fmaf(s, v.x, acc.x); acc.y = fmaf(s, v.y, acc.y);
  acc.z = fmaf(s, v.z, acc.z); acc.w = fmaf(s, v.w, acc.w);
}
__device__ __forceinline__ float dot4(const float4& a, const float* w) {
  return fmaf(a.x, w[0], fmaf(a.y, w[1], fmaf(a.z, w[2], a.w * w[3])));
}

// Group barrier: counter add + poll at MALL. Callers drain vmcnt first.
__device__ __forceinline__ void group_barrier(unsigned* cnt, unsigned target) {
  __syncthreads();
  if (threadIdx.x == 0) {
    __hip_atomic_fetch_add(cnt, 1u, __ATOMIC_RELAXED, __HIP_MEMORY_SCOPE_AGENT);
    while (__hip_atomic_load(cnt, __ATOMIC_RELAXED, __HIP_MEMORY_SCOPE_AGENT) < target)
      __builtin_amdgcn_s_sleep(1);
    asm volatile("" ::: "memory");
  }
  __syncthreads();
}

extern "C" __global__ void __launch_bounds__(NT, 1)
rnn_persistent(const float* __restrict__ x,      // [4][256][64][32]
               const float* __restrict__ Wcell,  // [4][544][512]
               const float* __restrict__ bcell,  // [4][512]
               const float* __restrict__ Wcomb,  // [3][1024]
               const float* __restrict__ bcomb,  // [3]
               const float* __restrict__ Wout,   // [512]
               float* __restrict__ out,          // [1024] = [lane][batch]
               float* __restrict__ ws)
{
  const int wg  = blockIdx.x;
  const int g   = wg >> 2;        // batch group (0..63)
  const int sl  = wg & 3;         // S-slice (0..3)
  const int r0  = g * RPG;
  const int sb  = sl * SW;
  const int tid = threadIdx.x;

  const int row  = tid >> 6;      // 0..3 == wave id (stage/gate/out mapping)
  const int lane = tid & 63;
  const int ks   = lane * 8;      // global k-column base, 8 contiguous floats

  const int kc = tid >> 4;        // 0..15: k-chunk [kc*32, kc*32+32)
  const int sp = tid & 15;        // 0..15: s-cols [sp*8, sp*8+8) within slice

  // LDS: h rows in padded 16-float blocks (block b at b*20 -> matvec's 4
  // concurrent kc addresses land on distinct bank-quads; broadcast reads free)
  __shared__ float h_lds[RPG * 640];      // 10.0 KB
  __shared__ float red[16 * RPG * SW];    // 32 KB  [kc][r][s]

  unsigned* ctl  = (unsigned*)(ws + CTL_OFF);
  unsigned* gcnt = ctl + 0;
  unsigned* gflg = ctl + 1;
  unsigned* cnt  = ctl + 8 + g * 4;
  unsigned* flg  = ctl + 8 + g * 4 + 1;

  // ---- one-time poison cleanup + grid-start barrier ----------------------
  // Harness re-poisons ws with 0xAA through normal (L2-dirty) stores. Our
  // state writes bypass L2 -> a later eviction of a dirty poison line would
  // overwrite MALL state. __threadfence() emits buffer_wbl2/inv (cleans this
  // XCD's L2); the global barrier ensures ALL XCDs are clean before any
  // coherent state store anywhere.
  if (tid == 0) {
    __threadfence();
    if (wg == 0) {
      __hip_atomic_store(gcnt, 0u, __ATOMIC_RELAXED, __HIP_MEMORY_SCOPE_AGENT);
      __hip_atomic_store(gflg, FLAG_MAGIC, __ATOMIC_RELEASE, __HIP_MEMORY_SCOPE_AGENT);
    }
    while (__hip_atomic_load(gflg, __ATOMIC_ACQUIRE, __HIP_MEMORY_SCOPE_AGENT) != FLAG_MAGIC)
      __builtin_amdgcn_s_sleep(1);
    __hip_atomic_fetch_add(gcnt, 1u, __ATOMIC_RELAXED, __HIP_MEMORY_SCOPE_AGENT);
    while (__hip_atomic_load(gcnt, __ATOMIC_RELAXED, __HIP_MEMORY_SCOPE_AGENT) < NWG)
      __builtin_amdgcn_s_sleep(1);
    if (sl == 0) {
      __hip_atomic_store(cnt, 0u, __ATOMIC_RELAXED, __HIP_MEMORY_SCOPE_AGENT);
      __hip_atomic_store(flg, FLAG_MAGIC, __ATOMIC_RELEASE, __HIP_MEMORY_SCOPE_AGENT);
    }
    while (__hip_atomic_load(flg, __ATOMIC_ACQUIRE, __HIP_MEMORY_SCOPE_AGENT) != FLAG_MAGIC)
      __builtin_amdgcn_s_sleep(1);
    asm volatile("" ::: "memory");
  }
  __syncthreads();

  unsigned phase = 0;

  for (int i = 0; i < NSEQ; ++i) {
    const float* Wc = Wcell + (size_t)i * (FIN + S) * S;

    // ---- recurrent weight slice in registers: 256 VGPRs ----
    float4 Ua[32], Ub[32];
    #pragma unroll
    for (int k = 0; k < 32; ++k) {
      const float* up = Wc + (size_t)(FIN + kc * 32 + k) * S + sb + sp * 8;
      Ua[k] = *(const float4*)up;
      Ub[k] = *(const float4*)(up + 4);
    }
    // ---- gate weights for this thread's 8 k-columns (regs, no LDS) ----
    float wgh[8], wgp[8];
    float bg = 0.0f;
    if (i > 0) {
      bg = bcomb[i - 1];
      const float* wgb = Wcomb + (size_t)(i - 1) * 2 * S;
      #pragma unroll
      for (int j = 0; j < 8; j += 4) {
        float4 a = *(const float4*)(wgb + ks + j);
        float4 b = *(const float4*)(wgb + S + ks + j);
        wgh[j] = a.x; wgh[j+1] = a.y; wgh[j+2] = a.z; wgh[j+3] = a.w;
        wgp[j] = b.x; wgp[j+1] = b.y; wgp[j+2] = b.z; wgp[j+3] = b.w;
      }
    }

    // ---- XW precompute: xw[t][b][sb+s] = x_t @ Wx + bc (WG-private slice) ----
    {
      const int s_ = tid & 127;
      const int q2 = tid >> 7;
      float wxr[FIN];
      #pragma unroll
      for (int f = 0; f < FIN; ++f) wxr[f] = Wc[(size_t)f * S + sb + s_];
      const float bcv = bcell[i * S + sb + s_];
      for (int t = q2; t < T; t += 2) {
        #pragma unroll
        for (int r = 0; r < RPG; ++r) {
          const float* xr = x + (((size_t)i * BATCH + r0 + r) * T + t) * FIN;
          float acc = bcv;
          #pragma unroll
          for (int f = 0; f < FIN; f += 4) {
            float4 xv = *(const float4*)(xr + f);
            acc = fmaf(xv.x, wxr[f],     acc);
            acc = fmaf(xv.y, wxr[f + 1], acc);
            acc = fmaf(xv.z, wxr[f + 2], acc);
            acc = fmaf(xv.w, wxr[f + 3], acc);
          }
          ws[XW_OFF + ((size_t)t * BATCH + r0 + r) * S + sb + s_] = acc;
        }
      }
    }
    __syncthreads();

    float*       stc = ws + ((i & 1) ? ST1_OFF : ST0_OFF);
    const float* stp = ws + ((i & 1) ? ST0_OFF : ST1_OFF);

    for (int t = 0; t < T; ++t) {
      // xw prefetch for the reduce phase (L1/L2-fast, overlaps everything)
      const int os = tid & 127, orr = tid >> 7;
      float xw0 = ws[XW_OFF + ((size_t)t * BATCH + r0 + orr) * S + sb + os];
      float xw1 = ws[XW_OFF + ((size_t)t * BATCH + r0 + 2 + orr) * S + sb + os];

      // ---- coherent stage: wave 'row' loads its full 2KB state row ----
      float4 h0, h1, p0, p1;
      const float* hp = stc + ((size_t)(t - 1) * BATCH + r0 + row) * S + ks;
      const float* pp = stp + ((size_t)t * BATCH + r0 + row) * S + ks;
      if (t > 0) {
        if (i > 0) cload16(h0, h1, p0, p1, hp, pp);
        else       cload8(h0, h1, hp);
      } else {
        h0 = make_float4(0.f, 0.f, 0.f, 0.f); h1 = h0;
        if (i > 0) cload8(p0, p1, pp);
      }

      // ---- gate: wave-local (row == wave), zero syncthreads ----
      if (i > 0) {
        float gp = dot4(h0, wgh) + dot4(h1, wgh + 4)
                 + dot4(p0, wgp) + dot4(p1, wgp + 4);
        #pragma unroll
        for (int m = 1; m < 64; m <<= 1) gp += __shfl_xor(gp, m, 64);
        const float w = 1.0f / (1.0f + __expf(-(gp + bg)));
        // hc = p + w*(h-p)
        h0.x = fmaf(w, h0.x - p0.x, p0.x); h0.y = fmaf(w, h0.y - p0.y, p0.y);
        h0.z = fmaf(w, h0.z - p0.z, p0.z); h0.w = fmaf(w, h0.w - p0.w, p0.w);
        h1.x = fmaf(w, h1.x - p1.x, p1.x); h1.y = fmaf(w, h1.y - p1.y, p1.y);
        h1.z = fmaf(w, h1.z - p1.z, p1.z); h1.w = fmaf(w, h1.w - p1.w, p1.w);
      }
      {
        const int hbase = row * 640 + (ks >> 4) * 20 + (ks & 15);
        *(float4*)&h_lds[hbase]     = h0;
        *(float4*)&h_lds[hbase + 4] = h1;
      }
      __syncthreads();

      // ---- matvec: thread (kc,sp): 32-k chunk x 8 s-cols x 4 rows ----
      float4 accA[RPG], accB[RPG];
      #pragma unroll
      for (int r = 0; r < RPG; ++r) {
        accA[r] = make_float4(0.f, 0.f, 0.f, 0.f);
        accB[r] = make_float4(0.f, 0.f, 0.f, 0.f);
      }
      #pragma unroll
      for (int r = 0; r < RPG; ++r) {
        const float* hb = &h_lds[r * 640 + kc * 40];
        float hk[32];
        #pragma unroll
        for (int b2 = 0; b2 < 2; ++b2) {
          const float* base = hb + b2 * 20;
          #pragma unroll
          for (int q = 0; q < 4; ++q) {
            float4 v = *(const float4*)(base + q * 4);  // bank-quads disjoint per kc
            hk[b2*16 + q*4 + 0] = v.x; hk[b2*16 + q*4 + 1] = v.y;
            hk[b2*16 + q*4 + 2] = v.z; hk[b2*16 + q*4 + 3] = v.w;
          }
        }
        #pragma unroll
        for (int k = 0; k < 32; ++k) {
          fma4(accA[r], hk[k], Ua[k]);
          fma4(accB[r], hk[k], Ub[k]);
        }
      }
      #pragma unroll
      for (int r = 0; r < RPG; ++r) {
        float* rp = &red[(kc * RPG + r) * SW + sp * 8];
        *(float4*)rp       = accA[r];
        *(float4*)(rp + 4) = accB[r];
      }
      __syncthreads();

      // ---- reduce 16 k-chunks + tanh + coherent store ----
      #pragma unroll
      for (int half = 0; half < 2; ++half) {
        const int r = half * 2 + orr;
        float sum = half ? xw1 : xw0;
        #pragma unroll
        for (int c = 0; c < 16; ++c) sum += red[(c * RPG + r) * SW + os];
        const float a  = fabsf(sum);
        const float e  = __expf(2.0f * a);
        const float th = copysignf(1.0f - 2.0f / (e + 1.0f), sum);
        cstore1(stc + ((size_t)t * BATCH + r0 + r) * S + sb + os, th);
      }

      ++phase;
      asm volatile("s_waitcnt vmcnt(0)" ::: "memory");  // cstores at MALL
      group_barrier(cnt, (unsigned)SLICES * phase);
    }

    // ---- final output: out[i*256 + b] = h_T[b] . Wout (sl==0 WGs) ----
    if (sl == 0) {
      float4 a, b;
      cload8(a, b, stc + ((size_t)(T - 1) * BATCH + r0 + row) * S + ks);
      float4 w0 = *(const float4*)(Wout + ks);
      float4 w1 = *(const float4*)(Wout + ks + 4);
      float acc = dot4(a, (const float*)&w0) + dot4(b, (const float*)&w1);
      #pragma unroll
      for (int m = 1; m < 64; m <<= 1) acc += __shfl_xor(acc, m, 64);
      if (lane == 0) out[i * BATCH + r0 + row] = acc;
    }
  }
}

extern "C" void kernel_launch(void* const* d_in, const int* in_sizes, int n_in,
                              void* d_out, int out_size, void* d_ws, size_t ws_size,
                              hipStream_t stream) {
  (void)in_sizes; (void)n_in; (void)out_size; (void)ws_size;
  rnn_persistent<<<dim3(NWG), dim3(NT), 0, stream>>>(
      (const float*)d_in[0],   // inputs
      (const float*)d_in[1],   // W_cell
      (const float*)d_in[2],   // b_cell
      (const float*)d_in[3],   // W_comb
      (const float*)d_in[4],   // b_comb
      (const float*)d_in[5],   // W_out
      (float*)d_out,
      (float*)d_ws);
}

// Round 4
// 819.311 us; speedup vs baseline: 3.7704x; 3.7704x over previous
//
#include <hip/hip_runtime.h>
#include <math.h>

// Problem constants
#define NSEQ 4
#define BATCH 256
#define T 64
#define FIN 32
#define S 512

// Pipelined decomposition: 4 lanes run CONCURRENTLY (lane i lags lane i-1 by
// one step). Per lane: 16 groups x 16 rows, 4 slice-WGs x 128 cols.
// 4 lanes x 16 grp x 4 sl = 256 WGs, NT=512 (8 waves, 2/SIMD).
#define NT 512
#define NWG 256
#define RPG 16
#define SW 128
#define DEPTH 4      // state ring depth (steps)

// ws float offsets
#define RING_SZ  (4ull * DEPTH * BATCH * S)   // [lane][slot][row256][512] = 8 MB
#define OUTP_OFF RING_SZ                       // [lane][grp][sl][16] partial outs
#define CTL_OFF  (RING_SZ + 4096ull)           // counters: gid*32 uints, flag at +16

#define FLAG_MAGIC 0x13572468u

#define HS 516   // h_lds row stride (pad: 4-way max on staged writes)
#define RS 130   // red row stride (2-way only on float2 ops)

__device__ __forceinline__ unsigned ld_cnt(const unsigned* p) {
  return __hip_atomic_load(p, __ATOMIC_RELAXED, __HIP_MEMORY_SCOPE_AGENT);
}

// ---- coherent ring I/O: device-coherent (MALL) via sc0 sc1 asm ------------
// Loads are batched per asm block (one vmcnt drain) and mapped so each
// wave-instruction covers contiguous 512 B per row -> fully packed fetches
// (R3's 4.3x FETCH inflation came from sparse per-lane 32B requests).
__device__ __forceinline__ void cstore1(float* p, float v) {
  asm volatile("global_store_dword %0, %1, off sc0 sc1" :: "v"(p), "v"(v) : "memory");
}
__device__ __forceinline__ float cload1(const float* p) {
  float v;
  asm volatile("global_load_dword %0, %1, off sc0 sc1\n\ts_waitcnt vmcnt(0)"
               : "=v"(v) : "v"(p) : "memory");
  return v;
}
__device__ __forceinline__ void cload_row(float4* d, const float* p) {
  asm volatile(
      "global_load_dwordx4 %0, %4, off sc0 sc1\n\t"
      "global_load_dwordx4 %1, %4, off offset:512 sc0 sc1\n\t"
      "global_load_dwordx4 %2, %4, off offset:1024 sc0 sc1\n\t"
      "global_load_dwordx4 %3, %4, off offset:1536 sc0 sc1\n\t"
      "s_waitcnt vmcnt(0)"
      : "=&v"(d[0]), "=&v"(d[1]), "=&v"(d[2]), "=&v"(d[3])
      : "v"(p) : "memory");
}
__device__ __forceinline__ void cload_row2(float4* h, float4* q,
                                           const float* ph, const float* pp) {
  asm volatile(
      "global_load_dwordx4 %0, %8, off sc0 sc1\n\t"
      "global_load_dwordx4 %1, %8, off offset:512 sc0 sc1\n\t"
      "global_load_dwordx4 %2, %8, off offset:1024 sc0 sc1\n\t"
      "global_load_dwordx4 %3, %8, off offset:1536 sc0 sc1\n\t"
      "global_load_dwordx4 %4, %9, off sc0 sc1\n\t"
      "global_load_dwordx4 %5, %9, off offset:512 sc0 sc1\n\t"
      "global_load_dwordx4 %6, %9, off offset:1024 sc0 sc1\n\t"
      "global_load_dwordx4 %7, %9, off offset:1536 sc0 sc1\n\t"
      "s_waitcnt vmcnt(0)"
      : "=&v"(h[0]), "=&v"(h[1]), "=&v"(h[2]), "=&v"(h[3]),
        "=&v"(q[0]), "=&v"(q[1]), "=&v"(q[2]), "=&v"(q[3])
      : "v"(ph), "v"(pp) : "memory");
}
__device__ __forceinline__ void fma2(float2& a, float s, float2 u) {
  a.x = fmaf(s, u.x, a.x); a.y = fmaf(s, u.y, a.y);
}

extern "C" __global__ void __launch_bounds__(NT, 2)
rnn_pipe(const float* __restrict__ x,      // [4][256][64][32]
         const float* __restrict__ Wcell,  // [4][544][512]
         const float* __restrict__ bcell,  // [4][512]
         const float* __restrict__ Wcomb,  // [3][1024]
         const float* __restrict__ bcomb,  // [3]
         const float* __restrict__ Wout,   // [512]
         float* __restrict__ out,          // [1024] = [lane][batch]
         float* __restrict__ ws)
{
  const int b   = blockIdx.x;
  // XCD-locality swizzle (perf heuristic only; correctness never depends on it)
  const int gid  = (b & 7) * 8 + ((b >> 3) >> 2);  // 0..63
  const int sl   = (b >> 3) & 3;                   // slice 0..3
  const int lane = gid >> 4;                       // 0..3
  const int grp  = gid & 15;                       // 0..15
  const int r0 = grp * RPG, sb = sl * SW;
  const int tid = threadIdx.x;
  const int wv  = tid >> 6;

  __shared__ float h_lds[RPG * HS];     // 33.0 KB gated hc rows [16][516]
  __shared__ float red[8 * 4 * RS];     // 16.6 KB k-partials [kc8][r4][130]
  __shared__ float x_lds[RPG * FIN];    //  2.0 KB x block for this step
  __shared__ float wg_lds[2 * S];       //  4.0 KB gate weights
  __shared__ float obuf[64];

  float* ring = ws;
  unsigned* ctl      = (unsigned*)(ws + CTL_OFF);
  unsigned* cnt_own  = ctl + gid * 32;
  unsigned* flg_own  = cnt_own + 16;
  unsigned* cnt_prod = ctl + (gid - 16) * 32;  // valid iff lane>0
  unsigned* cnt_cons = ctl + (gid + 16) * 32;  // valid iff lane<3

  // ---- init handshake (poison-safe: flag != MAGIC until counter zeroed) ----
  if (sl == 0 && tid == 0) {
    __hip_atomic_store(cnt_own, 0u, __ATOMIC_RELAXED, __HIP_MEMORY_SCOPE_AGENT);
    __hip_atomic_store(flg_own, FLAG_MAGIC, __ATOMIC_RELEASE, __HIP_MEMORY_SCOPE_AGENT);
  }
  if (tid == 0) {
    while (__hip_atomic_load(flg_own, __ATOMIC_ACQUIRE, __HIP_MEMORY_SCOPE_AGENT) != FLAG_MAGIC)
      __builtin_amdgcn_s_sleep(1);
    if (lane > 0)
      while (__hip_atomic_load(cnt_prod + 16, __ATOMIC_ACQUIRE, __HIP_MEMORY_SCOPE_AGENT) != FLAG_MAGIC)
        __builtin_amdgcn_s_sleep(1);
    if (lane < 3)
      while (__hip_atomic_load(cnt_cons + 16, __ATOMIC_ACQUIRE, __HIP_MEMORY_SCOPE_AGENT) != FLAG_MAGIC)
        __builtin_amdgcn_s_sleep(1);
  }
  __syncthreads();

  // ---- per-lane constants (each WG owns ONE lane -> loaded once) ----
  const float* Wc = Wcell + (size_t)lane * (FIN + S) * S;
  // matvec role: kc = wave (64-k chunk), sp -> 2 cols
  const int kc = tid >> 6, sp = tid & 63;
  float2 U2[64];  // 128 VGPR recurrent-weight slice
  #pragma unroll
  for (int k = 0; k < 64; ++k)
    U2[k] = *(const float2*)(Wc + (size_t)(FIN + kc * 64 + k) * S + sb + sp * 2);
  // reduce role: row-quarter rr, one col
  const int rr = tid >> 7, col = tid & 127;
  float wx[FIN];  // x-weight column (xw computed on the fly; no XW array)
  #pragma unroll
  for (int f = 0; f < FIN; ++f) wx[f] = Wc[(size_t)f * S + sb + col];
  const float bcv = bcell[lane * S + sb + col];
  for (int idx = tid; idx < 2 * S; idx += NT)
    wg_lds[idx] = (lane > 0) ? Wcomb[(size_t)(lane - 1) * 2 * S + idx] : 0.0f;
  const float bg = (lane > 0) ? bcomb[lane - 1] : 0.0f;
  // gate/stage role
  const int grow = tid >> 5, gch = tid & 31;
  __syncthreads();

  float oacc[4] = {0.f, 0.f, 0.f, 0.f};

  for (int t = 0; t < T; ++t) {
    // ---- phase A: x stage + split-phase waits ----
    x_lds[tid] = x[(((size_t)lane * BATCH + r0 + grow) * T + t) * FIN + gch];
    if (tid == 0) {
      if (t > 0)                 while (ld_cnt(cnt_own)  < 4u * (unsigned)t) {}
      if (lane > 0)              while (ld_cnt(cnt_prod) < 4u * (unsigned)(t + 1)) {}
      if (lane < 3 && t >= DEPTH) while (ld_cnt(cnt_cons) < 4u * (unsigned)(t - 3)) {}
    }
    __syncthreads();

    // ---- phase B: coherent loads + wave-local gate + stage hc ----
    float4 hv[4], pv[4];
    const float* hb = ring + ((size_t)(lane * DEPTH + ((t - 1) & 3)) * BATCH + r0 + grow) * S + gch * 4;
    const float* pb = ring + ((size_t)((lane - 1) * DEPTH + (t & 3)) * BATCH + r0 + grow) * S + gch * 4;
    if (t > 0) {
      if (lane > 0) cload_row2(hv, pv, hb, pb);
      else          cload_row(hv, hb);
    } else {
      #pragma unroll
      for (int j = 0; j < 4; ++j) hv[j] = make_float4(0.f, 0.f, 0.f, 0.f);
      if (lane > 0) cload_row(pv, pb);
    }
    if (lane > 0) {
      float gs = 0.0f;
      #pragma unroll
      for (int j = 0; j < 4; ++j) {
        const float* wh = &wg_lds[j * 128 + gch * 4];
        const float* wp = wh + S;
        gs += hv[j].x * wh[0] + hv[j].y * wh[1] + hv[j].z * wh[2] + hv[j].w * wh[3];
        gs += pv[j].x * wp[0] + pv[j].y * wp[1] + pv[j].z * wp[2] + pv[j].w * wp[3];
      }
      gs += __shfl_xor(gs, 1);  gs += __shfl_xor(gs, 2);  gs += __shfl_xor(gs, 4);
      gs += __shfl_xor(gs, 8);  gs += __shfl_xor(gs, 16);  // rows are 32-lane halves
      const float w = 1.0f / (1.0f + __expf(-(gs + bg)));
      #pragma unroll
      for (int j = 0; j < 4; ++j) {  // hc = p + w*(h-p)
        hv[j].x = fmaf(w, hv[j].x - pv[j].x, pv[j].x);
        hv[j].y = fmaf(w, hv[j].y - pv[j].y, pv[j].y);
        hv[j].z = fmaf(w, hv[j].z - pv[j].z, pv[j].z);
        hv[j].w = fmaf(w, hv[j].w - pv[j].w, pv[j].w);
      }
    }
    #pragma unroll
    for (int j = 0; j < 4; ++j)
      *(float4*)&h_lds[grow * HS + j * 128 + gch * 4] = hv[j];
    __syncthreads();

    // ---- phases C/D: matvec + reduce in 4 row-quarters (LDS budget) ----
    float* slot = ring + ((size_t)(lane * DEPTH + (t & 3)) * BATCH + r0) * S + sb;
    #pragma unroll
    for (int q = 0; q < 4; ++q) {
      #pragma unroll
      for (int r4 = 0; r4 < 4; ++r4) {
        const float* hrow = &h_lds[(q * 4 + r4) * HS + kc * 64];
        float2 a = make_float2(0.f, 0.f);
        #pragma unroll
        for (int u = 0; u < 16; ++u) {
          float4 h4 = *(const float4*)(hrow + u * 4);  // broadcast (uniform/wave)
          fma2(a, h4.x, U2[u * 4 + 0]); fma2(a, h4.y, U2[u * 4 + 1]);
          fma2(a, h4.z, U2[u * 4 + 2]); fma2(a, h4.w, U2[u * 4 + 3]);
        }
        *(float2*)&red[(kc * 4 + r4) * RS + sp * 2] = a;
      }
      __syncthreads();
      {
        const int r = q * 4 + rr;
        float s2 = bcv;
        #pragma unroll
        for (int f = 0; f < FIN; ++f) s2 = fmaf(x_lds[r * FIN + f], wx[f], s2);
        #pragma unroll
        for (int k8 = 0; k8 < 8; ++k8) s2 += red[(k8 * 4 + rr) * RS + col];
        const float aa = fabsf(s2), ee = __expf(2.0f * aa);
        const float th = copysignf(1.0f - 2.0f / (ee + 1.0f), s2);
        cstore1(slot + (size_t)r * S + col, th);
        if (t == T - 1) oacc[q] = fmaf(th, Wout[sb + col], oacc[q]);
      }
      __syncthreads();
    }
    // ---- arrive (split-phase: waiting happens at next step's phase A) ----
    if (tid == 0)
      __hip_atomic_fetch_add(cnt_own, 1u, __ATOMIC_RELAXED, __HIP_MEMORY_SCOPE_AGENT);
  }

  // ---- output: out[lane*256 + r] = h_T[r] . Wout ----
  #pragma unroll
  for (int q = 0; q < 4; ++q) {
    float v = oacc[q];
    v += __shfl_xor(v, 1);  v += __shfl_xor(v, 2);  v += __shfl_xor(v, 4);
    v += __shfl_xor(v, 8);  v += __shfl_xor(v, 16); v += __shfl_xor(v, 32);
    if ((tid & 63) == 0) obuf[q * 8 + wv] = v;  // row q*4+(wv>>1), 2 partials/row
  }
  __syncthreads();
  if (tid < 16) {
    const int q = tid >> 2, a = tid & 3;
    const float v = obuf[q * 8 + 2 * a] + obuf[q * 8 + 2 * a + 1];
    cstore1(ws + OUTP_OFF + (size_t)(((lane * 16 + grp) * 4 + sl) * 16 + q * 4 + a), v);
  }
  __syncthreads();
  if (tid == 0)
    __hip_atomic_fetch_add(cnt_own, 1u, __ATOMIC_RELAXED, __HIP_MEMORY_SCOPE_AGENT);
  if (sl == 0) {
    if (tid == 0)
      while (ld_cnt(cnt_own) < 4u * (unsigned)(T + 1)) {}
    __syncthreads();
    if (tid < 64) {
      const int sli = tid >> 4, r = tid & 15;
      obuf[tid] = cload1(ws + OUTP_OFF + (size_t)(((lane * 16 + grp) * 4 + sli) * 16 + r));
    }
    __syncthreads();
    if (tid < 16)
      out[lane * BATCH + r0 + tid] = obuf[tid] + obuf[16 + tid] + obuf[32 + tid] + obuf[48 + tid];
  }
}

extern "C" void kernel_launch(void* const* d_in, const int* in_sizes, int n_in,
                              void* d_out, int out_size, void* d_ws, size_t ws_size,
                              hipStream_t stream) {
  (void)in_sizes; (void)n_in; (void)out_size; (void)ws_size;
  rnn_pipe<<<dim3(NWG), dim3(NT), 0, stream>>>(
      (const float*)d_in[0],   // inputs
      (const float*)d_in[1],   // W_cell
      (const float*)d_in[2],   // b_cell
      (const float*)d_in[3],   // W_comb
      (const float*)d_in[4],   // b_comb
      (const float*)d_in[5],   // W_out
      (float*)d_out,
      (float*)d_ws);
}